// Round 1
// baseline (320.327 us; speedup 1.0000x reference)
//
#include <hip/hip_runtime.h>

#define ROW_L 32000
#define NTHREADS 256

__global__ __launch_bounds__(NTHREADS) void oracle_best_expert_kernel(
    const int* __restrict__ labels,
    const float* __restrict__ g0,
    const float* __restrict__ g1,
    const float* __restrict__ g2,
    const float* __restrict__ g3,
    float* __restrict__ out)
{
    const int b = blockIdx.x;
    const size_t row = (size_t)b * ROW_L;
    const float* ptrs[4] = { g0 + row, g1 + row, g2 + row, g3 + row };

    const int tid = threadIdx.x;

    // Per-thread running argmax per expert. Indices are visited in increasing
    // order per thread, so strict '>' keeps the FIRST max (jnp.argmax tie rule).
    float vmax[4];
    int   vidx[4];
#pragma unroll
    for (int e = 0; e < 4; ++e) { vmax[e] = -__builtin_inff(); vidx[e] = 0; }

    const int NV = ROW_L / 4;  // 8000 float4 per row
    for (int i = tid; i < NV; i += NTHREADS) {
        const int base = i * 4;
#pragma unroll
        for (int e = 0; e < 4; ++e) {
            const float4 v = reinterpret_cast<const float4*>(ptrs[e])[i];
            if (v.x > vmax[e]) { vmax[e] = v.x; vidx[e] = base + 0; }
            if (v.y > vmax[e]) { vmax[e] = v.y; vidx[e] = base + 1; }
            if (v.z > vmax[e]) { vmax[e] = v.z; vidx[e] = base + 2; }
            if (v.w > vmax[e]) { vmax[e] = v.w; vidx[e] = base + 3; }
        }
    }

    // Wave (64-lane) reduction with explicit tie-break: larger value wins;
    // equal value -> smaller index wins (first occurrence).
#pragma unroll
    for (int off = 32; off >= 1; off >>= 1) {
#pragma unroll
        for (int e = 0; e < 4; ++e) {
            const float ov = __shfl_down(vmax[e], off, 64);
            const int   oi = __shfl_down(vidx[e], off, 64);
            if (ov > vmax[e] || (ov == vmax[e] && oi < vidx[e])) {
                vmax[e] = ov; vidx[e] = oi;
            }
        }
    }

    // Cross-wave reduction via tiny LDS (4 waves x 4 experts).
    __shared__ float s_max[4][4];
    __shared__ int   s_idx[4][4];
    __shared__ int   s_best;
    const int wave = tid >> 6;
    const int lane = tid & 63;
    if (lane == 0) {
#pragma unroll
        for (int e = 0; e < 4; ++e) { s_max[wave][e] = vmax[e]; s_idx[wave][e] = vidx[e]; }
    }
    __syncthreads();

    if (tid == 0) {
        const int lab = labels[b];
        int best = -1;
#pragma unroll
        for (int e = 0; e < 4; ++e) {
            float m  = s_max[0][e];
            int   ix = s_idx[0][e];
#pragma unroll
            for (int w = 1; w < 4; ++w) {
                const float ov = s_max[w][e];
                const int   oi = s_idx[w][e];
                if (ov > m || (ov == m && oi < ix)) { m = ov; ix = oi; }
            }
            if (ix == lab && best < 0) best = e;   // first correct expert
        }
        if (best < 0) {
            // No expert correct: argmax over label logits (first max wins).
            float bm = ptrs[0][lab];
            best = 0;
#pragma unroll
            for (int e = 1; e < 4; ++e) {
                const float v = ptrs[e][lab];
                if (v > bm) { bm = v; best = e; }
            }
        }
        s_best = best;
    }
    __syncthreads();

    // Copy the chosen expert's row to the output (bit-exact).
    const float* __restrict__ src = ptrs[s_best];
    float* __restrict__ dst = out + row;
    for (int i = tid; i < NV; i += NTHREADS) {
        reinterpret_cast<float4*>(dst)[i] = reinterpret_cast<const float4*>(src)[i];
    }
}

extern "C" void kernel_launch(void* const* d_in, const int* in_sizes, int n_in,
                              void* d_out, int out_size, void* d_ws, size_t ws_size,
                              hipStream_t stream) {
    const int*   labels = (const int*)d_in[0];
    const float* g0     = (const float*)d_in[1];
    const float* g1     = (const float*)d_in[2];
    const float* g2     = (const float*)d_in[3];
    const float* g3     = (const float*)d_in[4];
    float*       out    = (float*)d_out;

    const int B = in_sizes[0];  // 2048 rows
    oracle_best_expert_kernel<<<B, NTHREADS, 0, stream>>>(labels, g0, g1, g2, g3, out);
}

// Round 2
// 272.821 us; speedup vs baseline: 1.1741x; 1.1741x over previous
//
#include <hip/hip_runtime.h>

#define ROW_L 32000
#define NT    256
#define NV    (ROW_L / 4)            // 8000 float4 per row
#define UF    4                      // float4 batched per expert per iteration
#define STEP  (NT * UF)              // 1024
#define FULLV ((NV / STEP) * STEP)   // 7168

typedef float f32x4 __attribute__((ext_vector_type(4)));

__global__ __launch_bounds__(NT) void oracle_best_expert_kernel(
    const int* __restrict__ labels,
    const float* __restrict__ g0,
    const float* __restrict__ g1,
    const float* __restrict__ g2,
    const float* __restrict__ g3,
    float* __restrict__ out)
{
    const int b = blockIdx.x;
    const size_t row = (size_t)b * ROW_L;
    const float* __restrict__ p0 = g0 + row;
    const float* __restrict__ p1 = g1 + row;
    const float* __restrict__ p2 = g2 + row;
    const float* __restrict__ p3 = g3 + row;
    const f32x4* __restrict__ q0 = (const f32x4*)p0;
    const f32x4* __restrict__ q1 = (const f32x4*)p1;
    const f32x4* __restrict__ q2 = (const f32x4*)p2;
    const f32x4* __restrict__ q3 = (const f32x4*)p3;

    const int tid = threadIdx.x;

    // Per-thread running argmax per expert. Each thread visits its indices in
    // increasing order, so strict '>' keeps the FIRST max (jnp.argmax rule).
    float vmax[4];
    int   vidx[4];
#pragma unroll
    for (int e = 0; e < 4; ++e) { vmax[e] = -__builtin_inff(); vidx[e] = 0; }

    // Main scan: batch 16 float4 loads (4 experts x UF) before any compare,
    // so one vmcnt wait covers the whole batch -> high MLP.
    for (int i0 = tid; i0 < FULLV; i0 += STEP) {
        f32x4 va[4][UF];
#pragma unroll
        for (int u = 0; u < UF; ++u) {
            const int i = i0 + u * NT;
            va[0][u] = q0[i];
            va[1][u] = q1[i];
            va[2][u] = q2[i];
            va[3][u] = q3[i];
        }
#pragma unroll
        for (int u = 0; u < UF; ++u) {
            const int base = (i0 + u * NT) * 4;
#pragma unroll
            for (int e = 0; e < 4; ++e) {
                const f32x4 v = va[e][u];
                if (v.x > vmax[e]) { vmax[e] = v.x; vidx[e] = base + 0; }
                if (v.y > vmax[e]) { vmax[e] = v.y; vidx[e] = base + 1; }
                if (v.z > vmax[e]) { vmax[e] = v.z; vidx[e] = base + 2; }
                if (v.w > vmax[e]) { vmax[e] = v.w; vidx[e] = base + 3; }
            }
        }
    }
    // Tail (NV - FULLV = 832 float4)
    for (int i = FULLV + tid; i < NV; i += NT) {
        const int base = i * 4;
        const f32x4 v0 = q0[i], v1 = q1[i], v2 = q2[i], v3 = q3[i];
        const f32x4 vv[4] = { v0, v1, v2, v3 };
#pragma unroll
        for (int e = 0; e < 4; ++e) {
            const f32x4 v = vv[e];
            if (v.x > vmax[e]) { vmax[e] = v.x; vidx[e] = base + 0; }
            if (v.y > vmax[e]) { vmax[e] = v.y; vidx[e] = base + 1; }
            if (v.z > vmax[e]) { vmax[e] = v.z; vidx[e] = base + 2; }
            if (v.w > vmax[e]) { vmax[e] = v.w; vidx[e] = base + 3; }
        }
    }

    // Wave (64-lane) reduction; tie-break: larger value wins, equal value ->
    // smaller index wins (first occurrence).
#pragma unroll
    for (int off = 32; off >= 1; off >>= 1) {
#pragma unroll
        for (int e = 0; e < 4; ++e) {
            const float ov = __shfl_down(vmax[e], off, 64);
            const int   oi = __shfl_down(vidx[e], off, 64);
            if (ov > vmax[e] || (ov == vmax[e] && oi < vidx[e])) {
                vmax[e] = ov; vidx[e] = oi;
            }
        }
    }

    // Cross-wave reduction via tiny LDS (4 waves x 4 experts).
    __shared__ float s_max[4][4];
    __shared__ int   s_idx[4][4];
    __shared__ int   s_best;
    const int wave = tid >> 6;
    const int lane = tid & 63;
    if (lane == 0) {
#pragma unroll
        for (int e = 0; e < 4; ++e) { s_max[wave][e] = vmax[e]; s_idx[wave][e] = vidx[e]; }
    }
    __syncthreads();

    if (tid == 0) {
        const int lab = labels[b];
        int best = -1;
#pragma unroll
        for (int e = 0; e < 4; ++e) {
            float m  = s_max[0][e];
            int   ix = s_idx[0][e];
#pragma unroll
            for (int w = 1; w < 4; ++w) {
                const float ov = s_max[w][e];
                const int   oi = s_idx[w][e];
                if (ov > m || (ov == m && oi < ix)) { m = ov; ix = oi; }
            }
            if (ix == lab && best < 0) best = e;   // first correct expert
        }
        if (best < 0) {
            // No expert correct: argmax over label logits (first max wins).
            float bm = p0[lab];
            best = 0;
            const float c1 = p1[lab], c2 = p2[lab], c3 = p3[lab];
            if (c1 > bm) { bm = c1; best = 1; }
            if (c2 > bm) { bm = c2; best = 2; }
            if (c3 > bm) { bm = c3; best = 3; }
        }
        s_best = best;
    }
    __syncthreads();

    // Copy the chosen expert's row (bit-exact). Batched reads + non-temporal
    // stores (output is never re-read; keep L2/L3 for the inputs).
    const f32x4* __restrict__ src = (const f32x4*)((s_best == 0) ? p0 :
                                    (s_best == 1) ? p1 :
                                    (s_best == 2) ? p2 : p3);
    f32x4* __restrict__ dst = (f32x4*)(out + row);
    for (int i0 = tid; i0 < FULLV; i0 += STEP) {
        f32x4 t[UF];
#pragma unroll
        for (int u = 0; u < UF; ++u) t[u] = src[i0 + u * NT];
#pragma unroll
        for (int u = 0; u < UF; ++u)
            __builtin_nontemporal_store(t[u], &dst[i0 + u * NT]);
    }
    for (int i = FULLV + tid; i < NV; i += NT) {
        __builtin_nontemporal_store(src[i], &dst[i]);
    }
}

extern "C" void kernel_launch(void* const* d_in, const int* in_sizes, int n_in,
                              void* d_out, int out_size, void* d_ws, size_t ws_size,
                              hipStream_t stream) {
    const int*   labels = (const int*)d_in[0];
    const float* g0     = (const float*)d_in[1];
    const float* g1     = (const float*)d_in[2];
    const float* g2     = (const float*)d_in[3];
    const float* g3     = (const float*)d_in[4];
    float*       out    = (float*)d_out;

    const int B = in_sizes[0];  // 2048 rows
    oracle_best_expert_kernel<<<B, NT, 0, stream>>>(labels, g0, g1, g2, g3, out);
}

// Round 3
// 267.711 us; speedup vs baseline: 1.1965x; 1.0191x over previous
//
#include <hip/hip_runtime.h>

#define ROW_L 32000
#define NT    256
#define NV    (ROW_L / 4)   // 8000 float4 per row
#define UF    8             // float4 batched per wave per iteration

typedef float f32x4 __attribute__((ext_vector_type(4)));

__global__ __launch_bounds__(NT) void oracle_best_expert_kernel(
    const int* __restrict__ labels,
    const float* __restrict__ g0,
    const float* __restrict__ g1,
    const float* __restrict__ g2,
    const float* __restrict__ g3,
    float* __restrict__ out)
{
    const int b = blockIdx.x;
    const size_t row = (size_t)b * ROW_L;
    const float* __restrict__ p0 = g0 + row;
    const float* __restrict__ p1 = g1 + row;
    const float* __restrict__ p2 = g2 + row;
    const float* __restrict__ p3 = g3 + row;

    const int tid  = threadIdx.x;
    const int wave = tid >> 6;
    const int lane = tid & 63;

    __shared__ float s_labv[4];   // logits[e][label]
    __shared__ float s_max[4];
    __shared__ int   s_idx[4];
    __shared__ int   s_best;

    // Select this wave's expert row (select chain, not runtime-indexed array).
    const float* __restrict__ pw = (wave == 0) ? p0 :
                                   (wave == 1) ? p1 :
                                   (wave == 2) ? p2 : p3;
    const f32x4* __restrict__ q = (const f32x4*)pw;

    // Prefetch the label logit for this wave's expert; latency hides under
    // the scan (consumed only after the post-scan barrier).
    const int lab = labels[b];
    if (lane == 0) s_labv[wave] = pw[lab];

    // Scan: wave w reads expert w's whole row as one sequential stream.
    // Lane l visits float4 indices l, l+64, ... (strictly increasing), so
    // strict '>' keeps the FIRST max (jnp.argmax tie rule).
    float m  = -__builtin_inff();
    int   mi = 0;

    // 8000 = 15 * (8*64) + 5*64
#pragma unroll 1
    for (int it = 0; it < 15; ++it) {
        const int base = it * (UF * 64) + lane;
        f32x4 v[UF];
#pragma unroll
        for (int u = 0; u < UF; ++u) v[u] = q[base + u * 64];
#pragma unroll
        for (int u = 0; u < UF; ++u) {
            const int bi = (base + u * 64) * 4;
            if (v[u].x > m) { m = v[u].x; mi = bi + 0; }
            if (v[u].y > m) { m = v[u].y; mi = bi + 1; }
            if (v[u].z > m) { m = v[u].z; mi = bi + 2; }
            if (v[u].w > m) { m = v[u].w; mi = bi + 3; }
        }
    }
    {   // tail: 5 more float4 per lane
        const int base = 15 * (UF * 64) + lane;   // 7680 + lane
        f32x4 v[5];
#pragma unroll
        for (int u = 0; u < 5; ++u) v[u] = q[base + u * 64];
#pragma unroll
        for (int u = 0; u < 5; ++u) {
            const int bi = (base + u * 64) * 4;
            if (v[u].x > m) { m = v[u].x; mi = bi + 0; }
            if (v[u].y > m) { m = v[u].y; mi = bi + 1; }
            if (v[u].z > m) { m = v[u].z; mi = bi + 2; }
            if (v[u].w > m) { m = v[u].w; mi = bi + 3; }
        }
    }

    // 64-lane reduce; tie-break: equal value -> smaller index (first max).
#pragma unroll
    for (int off = 32; off >= 1; off >>= 1) {
        const float ov = __shfl_down(m, off, 64);
        const int   oi = __shfl_down(mi, off, 64);
        if (ov > m || (ov == m && oi < mi)) { m = ov; mi = oi; }
    }
    if (lane == 0) { s_max[wave] = m; s_idx[wave] = mi; }
    __syncthreads();

    if (tid == 0) {
        int best = -1;
#pragma unroll
        for (int e = 0; e < 4; ++e)
            if (best < 0 && s_idx[e] == lab) best = e;   // first correct expert
        if (best < 0) {
            float bm = s_labv[0]; best = 0;
#pragma unroll
            for (int e = 1; e < 4; ++e)
                if (s_labv[e] > bm) { bm = s_labv[e]; best = e; }  // first max
        }
        s_best = best;
    }
    __syncthreads();

    // Copy the winning row (bit-exact). Batched reads, non-temporal stores
    // (output is never re-read; keep cache capacity for the inputs).
    const int be = s_best;
    const f32x4* __restrict__ src = (const f32x4*)((be == 0) ? p0 :
                                                   (be == 1) ? p1 :
                                                   (be == 2) ? p2 : p3);
    f32x4* __restrict__ dst = (f32x4*)(out + row);
#pragma unroll 1
    for (int i0 = tid; i0 < NV; i0 += NT * UF) {
        f32x4 t[UF];
#pragma unroll
        for (int u = 0; u < UF; ++u) {
            const int i = i0 + u * NT;
            if (i < NV) t[u] = src[i];
        }
#pragma unroll
        for (int u = 0; u < UF; ++u) {
            const int i = i0 + u * NT;
            if (i < NV) __builtin_nontemporal_store(t[u], &dst[i]);
        }
    }
}

extern "C" void kernel_launch(void* const* d_in, const int* in_sizes, int n_in,
                              void* d_out, int out_size, void* d_ws, size_t ws_size,
                              hipStream_t stream) {
    const int*   labels = (const int*)d_in[0];
    const float* g0     = (const float*)d_in[1];
    const float* g1     = (const float*)d_in[2];
    const float* g2     = (const float*)d_in[3];
    const float* g3     = (const float*)d_in[4];
    float*       out    = (float*)d_out;

    const int B = in_sizes[0];  // 2048 rows
    oracle_best_expert_kernel<<<B, NT, 0, stream>>>(labels, g0, g1, g2, g3, out);
}